// Round 18
// baseline (212.410 us; speedup 1.0000x reference)
//
#include <hip/hip_runtime.h>
#include <hip/hip_bf16.h>

// SrnmSpmm: out[b,s,n] = sum_k x[b,s,keep[k]] * values[n,k] + bias[n]
// keep: cols {8i, 8i+2} of D_IN=4096 -> K=1024. M = B*S = 16384, N = 4096.
//
// R18 = R17 with L2-locality remap: per round each XCD touches 4 A-panels +
// 8 B-panels (6 MB, vs 9 MB before) -> staging loads L2-hit, vmcnt(6) lead
// covers latency. GEMM schedule/swizzle/stores byte-identical to R17.
// Block i on XCD c, round r: btm = 8c + 4*(r>>1) + (i&3),
//                            btn = 8*(r&1) + (i>>2).

#define M_TOTAL 16384
#define DIN     4096
#define KDIM    1024
#define NDIM    4096

typedef unsigned short u16;
typedef unsigned int   u32;
typedef __bf16 bf16x8 __attribute__((ext_vector_type(8)));
typedef float  f32x4  __attribute__((ext_vector_type(4)));
typedef float  f32x16 __attribute__((ext_vector_type(16)));

typedef const void __attribute__((address_space(1)))* gp_t;
typedef void __attribute__((address_space(3)))*       lp_t;

__device__ __forceinline__ u16 f2bf(float f) {
    u32 u = __float_as_uint(f);
    u += 0x7FFFu + ((u >> 16) & 1u);   // round-to-nearest-even
    return (u16)(u >> 16);
}
__device__ __forceinline__ u32 pack2(float a, float b) {
    return (u32)f2bf(a) | ((u32)f2bf(b) << 16);
}

// Pass 1 (unchanged): compact x / cast values, NT loads, coalesced writes.
__global__ void prep_kernel(const float* __restrict__ x, uint2* __restrict__ xg2,
                            const float* __restrict__ vals, uint4* __restrict__ vb4) {
    const int tid = threadIdx.x;
    if (blockIdx.x < 4096) {
        int i = blockIdx.x * 256 + tid;
        const int stride = 4096 * 256;
#pragma unroll
        for (int it = 0; it < 4; ++it, i += stride) {
            const f32x4* p = (const f32x4*)(x + (size_t)i * 16);
            f32x4 f0 = __builtin_nontemporal_load(p);
            f32x4 f1 = __builtin_nontemporal_load(p + 2);
            xg2[i] = make_uint2(pack2(f0.x, f0.z), pack2(f1.x, f1.z));
        }
    } else {
        const int i = (blockIdx.x - 4096) * 256 + tid;
        const f32x4* p = (const f32x4*)(vals + (size_t)i * 8);
        f32x4 a = __builtin_nontemporal_load(p);
        f32x4 b = __builtin_nontemporal_load(p + 1);
        vb4[i] = make_uint4(pack2(a.x, a.y), pack2(a.z, a.w),
                            pack2(b.x, b.y), pack2(b.z, b.w));
    }
}

// ---------------- persistent 256x256 GEMM, 32x32x16 MFMA (R17 core) --------
#define LDSA(d, kh) (((d) * 2 + (kh)) * 16384)
#define LDSB(d, kh) (65536 + ((d) * 2 + (kh)) * 16384)

#define LOADA(d, kh, mh) { _Pragma("unroll") \
    for (int mm = 0; mm < 2; ++mm) { _Pragma("unroll") \
    for (int ks = 0; ks < 2; ++ks) \
        af[mm * 2 + ks] = *(const bf16x8*)(lds + LDSA(d, kh) \
            + (wr * 8 + ((mh) * 2 + mm) * 2) * 1024 + fl_base \
            + (((ks << 5) + acol) ^ aswz)); } }

#define LOADB(d, kh) { _Pragma("unroll") \
    for (int nn = 0; nn < 2; ++nn) { _Pragma("unroll") \
    for (int ks = 0; ks < 2; ++ks) \
        bfr[nn * 2 + ks] = *(const bf16x8*)(lds + LDSB(d, kh) \
            + (wc * 4 + nn * 2) * 1024 + fl_base \
            + (((ks << 5) + acol) ^ aswz)); } }

#define MFMA8(mh) { \
    __builtin_amdgcn_s_setprio(1); \
    _Pragma("unroll") for (int mm = 0; mm < 2; ++mm) \
    _Pragma("unroll") for (int nn = 0; nn < 2; ++nn) \
    _Pragma("unroll") for (int ks = 0; ks < 2; ++ks) \
        acc[(mh) * 2 + mm][nn] = __builtin_amdgcn_mfma_f32_32x32x16_bf16( \
            af[mm * 2 + ks], bfr[nn * 2 + ks], acc[(mh) * 2 + mm][nn], 0, 0, 0); \
    __builtin_amdgcn_s_setprio(0); }

#define BAR() __builtin_amdgcn_s_barrier()
#define VMCNT6() asm volatile("s_waitcnt vmcnt(6)" ::: "memory")

__global__ __launch_bounds__(512, 2) void gemm_kernel(
    const u16* __restrict__ A, const u16* __restrict__ Bv,
    const float* __restrict__ bias, float* __restrict__ C)
{
    __shared__ __align__(1024) char lds[131072];

    const int tid  = threadIdx.x;
    const int lane = tid & 63;
    const int wid  = tid >> 6;
    const int wr   = wid >> 2;      // 0..1
    const int wc   = wid & 3;       // 0..3

    // L2-locality mapping: XCD c, intra-XCD index i.
    const int bb = blockIdx.x;
    const int c  = bb & 7;
    const int i  = bb >> 3;         // 0..31

    // Staging lane pattern (pre-swizzled global addr; LDS dest linear).
    const int st_r0 = wid * 16 + (lane >> 2);
    const int st_ck = ((lane & 3) * 8) ^ ((tid & 32) >> 1) ^ ((tid & 64) >> 3);
    const int dst0 = tid * 16;

    // Panel pointers per round: btm = 8c + 4*(r>>1) + (i&3);
    //                           btn = 8*(r&1) + (i>>2).
    auto APan = [&](int rr) {
        const int btm = c * 8 + ((rr >> 1) & 1) * 4 + (i & 3);
        return A + (size_t)(btm * 256 + st_r0) * KDIM + st_ck;
    };
    auto BPan = [&](int rr) {
        const int btn = (rr & 1) * 8 + (i >> 2);
        return Bv + (size_t)(btn * 256 + st_r0) * KDIM + st_ck;
    };

    // Fragment ds_read lane constants (verified R11).
    const int fl_base = (lane & 15) * 64 + ((lane >> 4) & 1) * 1024;
    const int aswz    = (((lane >> 3) & 1) << 5) ^ (((lane >> 4) & 1) << 4);
    const int acol    = ((lane >> 5) & 1) * 16;

    // half-tile slot s: kt=s>>2, j=s&3 (0=A.kh0,1=B.kh0,2=A.kh1,3=B.kh1)
    auto STAGE = [&](const u16* as_, const u16* bs_, int s) {
        const int kt = s >> 2, j = s & 3;
        const int d = kt & 1, kh = (j >> 1) & 1;
        const int ko = kt * 64 + kh * 32;
        const u16* src = (j & 1) ? bs_ : as_;
        const int base = ((j & 1) ? 65536 : 0) + (d * 2 + kh) * 16384;
        __builtin_amdgcn_global_load_lds((gp_t)(src + ko),
            (lp_t)(lds + base + dst0), 16, 0, 0);
        __builtin_amdgcn_global_load_lds((gp_t)(src + 128 * KDIM + ko),
            (lp_t)(lds + base + 8192 + dst0), 16, 0, 0);
    };

    f32x16 acc[4][2] = {};
    bf16x8 af[4], bfr[4];

    // Prologue: stage round-0 K-tile 0 fully + 3 half-tiles of K-tile 1.
    {
        const u16* A0 = APan(0);
        const u16* B0 = BPan(0);
        STAGE(A0, B0, 0); STAGE(A0, B0, 1); STAGE(A0, B0, 2); STAGE(A0, B0, 3);
        STAGE(A0, B0, 4); STAGE(A0, B0, 5); STAGE(A0, B0, 6);
    }
    VMCNT6();
    BAR();

#pragma unroll 1
    for (int r = 0; r < 4; ++r) {
        const u16* Ar = APan(r);
        const u16* Br = BPan(r);
        const u16* An = APan(r < 3 ? r + 1 : r);   // r=3: dummy re-stage
        const u16* Bn = BPan(r < 3 ? r + 1 : r);

#pragma unroll 1
        for (int t = 0; t < 7; ++t) {
            const int s0 = 8 * t + 7;
            // ---- K-tile 2t (dbuf 0) ----
            LOADB(0, 0); LOADA(0, 0, 0); STAGE(Ar, Br, s0);     BAR(); MFMA8(0); BAR();
            LOADA(0, 0, 1);              STAGE(Ar, Br, s0 + 1); BAR(); MFMA8(1); BAR();
            LOADB(0, 1); LOADA(0, 1, 0); STAGE(Ar, Br, s0 + 2); BAR(); MFMA8(0); BAR();
            LOADA(0, 1, 1);              STAGE(Ar, Br, s0 + 3); BAR(); MFMA8(1);
            VMCNT6(); BAR();
            // ---- K-tile 2t+1 (dbuf 1) ----
            LOADB(1, 0); LOADA(1, 0, 0); STAGE(Ar, Br, s0 + 4); BAR(); MFMA8(0); BAR();
            LOADA(1, 0, 1);              STAGE(Ar, Br, s0 + 5); BAR(); MFMA8(1); BAR();
            LOADB(1, 1); LOADA(1, 1, 0); STAGE(Ar, Br, s0 + 6); BAR(); MFMA8(0); BAR();
            LOADA(1, 1, 1);              STAGE(Ar, Br, s0 + 7); BAR(); MFMA8(1);
            VMCNT6(); BAR();
        }
        // ---- tail: K-tiles 14/15; stage s63 then next round's slots 0..6 --
        LOADB(0, 0); LOADA(0, 0, 0); STAGE(Ar, Br, 63); BAR(); MFMA8(0); BAR();
        LOADA(0, 0, 1);              STAGE(An, Bn, 0);  BAR(); MFMA8(1); BAR();
        LOADB(0, 1); LOADA(0, 1, 0); STAGE(An, Bn, 1);  BAR(); MFMA8(0); BAR();
        LOADA(0, 1, 1);              STAGE(An, Bn, 2);  BAR(); MFMA8(1);
        VMCNT6(); BAR();
        LOADB(1, 0); LOADA(1, 0, 0); STAGE(An, Bn, 3);  BAR(); MFMA8(0); BAR();
        LOADA(1, 0, 1);              STAGE(An, Bn, 4);  BAR(); MFMA8(1); BAR();
        LOADB(1, 1); LOADA(1, 1, 0); STAGE(An, Bn, 5);  BAR(); MFMA8(0); BAR();
        LOADA(1, 1, 1);              STAGE(An, Bn, 6);  BAR(); MFMA8(1);
        VMCNT6(); BAR();

        // Epilogue round r: NT stores (R17 epilogue, btm/btn per round).
        const int btm = c * 8 + ((r >> 1) & 1) * 4 + (i & 3);
        const int btn = (r & 1) * 8 + (i >> 2);
        const int c_colb = btn * 256 + wc * 64 + (lane & 31);
        float bvr[2];
#pragma unroll
        for (int n = 0; n < 2; ++n) bvr[n] = bias[c_colb + n * 32];
        const int c_row0 = btm * 256 + wr * 128 + ((lane >> 5) & 1) * 4;
#pragma unroll
        for (int mi = 0; mi < 4; ++mi) {
#pragma unroll
            for (int n = 0; n < 2; ++n) {
                f32x16 a = acc[mi][n];
#pragma unroll
                for (int q = 0; q < 4; ++q) {
#pragma unroll
                    for (int rr = 0; rr < 4; ++rr) {
                        const int row = c_row0 + mi * 32 + q * 8 + rr;
                        __builtin_nontemporal_store(a[q * 4 + rr] + bvr[n],
                            &C[(size_t)row * NDIM + c_colb + n * 32]);
                    }
                }
#pragma unroll
                for (int z = 0; z < 16; ++z) acc[mi][n][z] = 0.f;
            }
        }
    }
}

extern "C" void kernel_launch(void* const* d_in, const int* in_sizes, int n_in,
                              void* d_out, int out_size, void* d_ws, size_t ws_size,
                              hipStream_t stream) {
    const float* x      = (const float*)d_in[0];
    const float* values = (const float*)d_in[1];
    const float* bias   = (const float*)d_in[2];
    float* out = (float*)d_out;

    // ws: xg bf16 [16384][1024] = 32 MB @ 0; values bf16 [4096][1024] @ 32 MB
    u16* xg = (u16*)d_ws;
    u16* vb = (u16*)((char*)d_ws + ((size_t)32 << 20));

    prep_kernel<<<6144, 256, 0, stream>>>(x, (uint2*)xg, values, (uint4*)vb);
    gemm_kernel<<<256, 512, 0, stream>>>(xg, vb, bias, out);
}

// Round 19
// 205.713 us; speedup vs baseline: 1.0326x; 1.0326x over previous
//
#include <hip/hip_runtime.h>
#include <hip/hip_bf16.h>

// SrnmSpmm: out[b,s,n] = sum_k x[b,s,keep[k]] * values[n,k] + bias[n]
// keep: cols {8i, 8i+2} of D_IN=4096 -> K=1024. M = B*S = 16384, N = 4096.
//
// R19 = R17/R11 verbatim — the measured optimum (205.5-206.4 us).
// Persistent 256-block 256x256 GEMM, 32x32x16 MFMA, BK=64 2-deep dbuf,
// vmcnt(6) schedule, st_16x32+bit4 swizzle, NT scalar C stores; prep kernel
// compacts x->bf16 + casts values at ~87% HBM roofline.
// Closed investigations: 8 schedule variants (all 148-210us gemm), fusion x3
// (scratch/fence/queue regressions), L2 remap (FETCH -33%, time neutral) ->
// critical path is the barrier-lockstep phase structure; this is the plateau.

#define M_TOTAL 16384
#define DIN     4096
#define KDIM    1024
#define NDIM    4096

typedef unsigned short u16;
typedef unsigned int   u32;
typedef __bf16 bf16x8 __attribute__((ext_vector_type(8)));
typedef float  f32x4  __attribute__((ext_vector_type(4)));
typedef float  f32x16 __attribute__((ext_vector_type(16)));

typedef const void __attribute__((address_space(1)))* gp_t;
typedef void __attribute__((address_space(3)))*       lp_t;

__device__ __forceinline__ u16 f2bf(float f) {
    u32 u = __float_as_uint(f);
    u += 0x7FFFu + ((u >> 16) & 1u);   // round-to-nearest-even
    return (u16)(u >> 16);
}
__device__ __forceinline__ u32 pack2(float a, float b) {
    return (u32)f2bf(a) | ((u32)f2bf(b) << 16);
}

// Pass 1: blocks [0,4096): compact x — each lane owns one 64B line (2 x
// 8-block): f32x4 @ +0 and @ +32B -> uint2 (kept cols 0,2). NT loads.
// Blocks [4096,6144): cast values, 8 floats/lane -> uint4. NT loads.
__global__ void prep_kernel(const float* __restrict__ x, uint2* __restrict__ xg2,
                            const float* __restrict__ vals, uint4* __restrict__ vb4) {
    const int tid = threadIdx.x;
    if (blockIdx.x < 4096) {
        int i = blockIdx.x * 256 + tid;
        const int stride = 4096 * 256;
#pragma unroll
        for (int it = 0; it < 4; ++it, i += stride) {
            const f32x4* p = (const f32x4*)(x + (size_t)i * 16);
            f32x4 f0 = __builtin_nontemporal_load(p);
            f32x4 f1 = __builtin_nontemporal_load(p + 2);
            xg2[i] = make_uint2(pack2(f0.x, f0.z), pack2(f1.x, f1.z));
        }
    } else {
        const int i = (blockIdx.x - 4096) * 256 + tid;
        const f32x4* p = (const f32x4*)(vals + (size_t)i * 8);
        f32x4 a = __builtin_nontemporal_load(p);
        f32x4 b = __builtin_nontemporal_load(p + 1);
        vb4[i] = make_uint4(pack2(a.x, a.y), pack2(a.z, a.w),
                            pack2(b.x, b.y), pack2(b.z, b.w));
    }
}

// ---------------- persistent 256x256 GEMM, 32x32x16 MFMA -------------------
// 512 threads = 8 waves (2M x 4N); wave tile 128x64 = 4m x 2n frags of 32x32.
// K-tile 64 = 2 K-halves (kh) x 2 K-steps (ks=16) each.
// Half-tile slot = 256 rows x 32 cols bf16 = 16 KiB = 2 gload_lds.
// LDS 128 KiB: A[dbuf][kh] @ (2d+kh)*16K, B @ +64K.
// Subtile [16r][32c] = 1 KiB; swizzle: byte ^= (row-bit3)<<5 ^ (row-bit4)<<4,
// applied on the pre-swizzled global SOURCE (gload dest linear) and on the
// ds_read address. Operand layout (32x32x16): row/col = lane&31,
// k = (lane>>5)*8 + j.  C/D: col = lane&31, row = (reg&3)+8*(reg>>2)+4*(lane>>5).

#define LDSA(d, kh) (((d) * 2 + (kh)) * 16384)
#define LDSB(d, kh) (65536 + ((d) * 2 + (kh)) * 16384)

#define LOADA(d, kh, mh) { _Pragma("unroll") \
    for (int mm = 0; mm < 2; ++mm) { _Pragma("unroll") \
    for (int ks = 0; ks < 2; ++ks) \
        af[mm * 2 + ks] = *(const bf16x8*)(lds + LDSA(d, kh) \
            + (wr * 8 + ((mh) * 2 + mm) * 2) * 1024 + fl_base \
            + (((ks << 5) + acol) ^ aswz)); } }

#define LOADB(d, kh) { _Pragma("unroll") \
    for (int nn = 0; nn < 2; ++nn) { _Pragma("unroll") \
    for (int ks = 0; ks < 2; ++ks) \
        bfr[nn * 2 + ks] = *(const bf16x8*)(lds + LDSB(d, kh) \
            + (wc * 4 + nn * 2) * 1024 + fl_base \
            + (((ks << 5) + acol) ^ aswz)); } }

#define MFMA8(mh) { \
    __builtin_amdgcn_s_setprio(1); \
    _Pragma("unroll") for (int mm = 0; mm < 2; ++mm) \
    _Pragma("unroll") for (int nn = 0; nn < 2; ++nn) \
    _Pragma("unroll") for (int ks = 0; ks < 2; ++ks) \
        acc[(mh) * 2 + mm][nn] = __builtin_amdgcn_mfma_f32_32x32x16_bf16( \
            af[mm * 2 + ks], bfr[nn * 2 + ks], acc[(mh) * 2 + mm][nn], 0, 0, 0); \
    __builtin_amdgcn_s_setprio(0); }

#define BAR() __builtin_amdgcn_s_barrier()
#define VMCNT6() asm volatile("s_waitcnt vmcnt(6)" ::: "memory")

__global__ __launch_bounds__(512, 2) void gemm_kernel(
    const u16* __restrict__ A, const u16* __restrict__ Bv,
    const float* __restrict__ bias, float* __restrict__ C)
{
    __shared__ __align__(1024) char lds[131072];

    const int tid  = threadIdx.x;
    const int lane = tid & 63;
    const int wid  = tid >> 6;
    const int wr   = wid >> 2;      // 0..1
    const int wc   = wid & 3;       // 0..3

    // Persistent mapping: XCD (bb&7) covers btm {8c..8c+7}; btn fixed/block.
    const int bb   = blockIdx.x;
    const int btm0 = (bb & 7) * 8 + (bb >> 7);
    const int btn  = (bb >> 3) & 15;

    // Staging source (pre-swizzled global addr; LDS dest linear).
    // Swizzle: elem ^= (tid-bit5 -> 16) ^ (tid-bit6 -> 8)  (byte bits 5,4).
    const int st_r0 = wid * 16 + (lane >> 2);
    const int st_ck = ((lane & 3) * 8) ^ ((tid & 32) >> 1) ^ ((tid & 64) >> 3);
    const u16* A0  = A  + (size_t)(btm0 * 256 + st_r0) * KDIM + st_ck;
    const u16* Bs0 = Bv + (size_t)(btn  * 256 + st_r0) * KDIM + st_ck;
    const int dst0 = tid * 16;

    // Fragment ds_read lane constants (rows = lane&31 span 2 subtiles).
    const int fl_base = (lane & 15) * 64 + ((lane >> 4) & 1) * 1024;
    const int aswz    = (((lane >> 3) & 1) << 5) ^ (((lane >> 4) & 1) << 4);
    const int acol    = ((lane >> 5) & 1) * 16;

    // half-tile slot s: kt=s>>2, j=s&3 (0=A.kh0,1=B.kh0,2=A.kh1,3=B.kh1)
    auto STAGE = [&](const u16* as_, int s) {
        const int kt = s >> 2, j = s & 3;
        const int d = kt & 1, kh = (j >> 1) & 1;
        const int ko = kt * 64 + kh * 32;
        const u16* src = (j & 1) ? Bs0 : as_;
        const int base = ((j & 1) ? 65536 : 0) + (d * 2 + kh) * 16384;
        __builtin_amdgcn_global_load_lds((gp_t)(src + ko),
            (lp_t)(lds + base + dst0), 16, 0, 0);
        __builtin_amdgcn_global_load_lds((gp_t)(src + 128 * KDIM + ko),
            (lp_t)(lds + base + 8192 + dst0), 16, 0, 0);
    };

    // bias (btn fixed): 2 scalars per lane (cols n*32 + lane&31).
    const int c_colb = btn * 256 + wc * 64 + (lane & 31);
    float bvr[2];
#pragma unroll
    for (int n = 0; n < 2; ++n) bvr[n] = bias[c_colb + n * 32];

    f32x16 acc[4][2] = {};
    bf16x8 af[4], bfr[4];

    // Prologue (once): stage K-tile 0 fully + 3 half-tiles of K-tile 1.
    STAGE(A0, 0); STAGE(A0, 1); STAGE(A0, 2); STAGE(A0, 3);
    STAGE(A0, 4); STAGE(A0, 5); STAGE(A0, 6);
    VMCNT6();
    BAR();

#pragma unroll 1
    for (int r = 0; r < 4; ++r) {
        const u16* Ar = A0 + (size_t)r * 512 * KDIM;
        const u16* An = (r < 3) ? (Ar + 512 * KDIM) : Ar;  // r=3: dummy re-stage

#pragma unroll 1
        for (int t = 0; t < 7; ++t) {
            const int s0 = 8 * t + 7;
            // ---- K-tile 2t (dbuf 0) ----
            LOADB(0, 0); LOADA(0, 0, 0); STAGE(Ar, s0);     BAR(); MFMA8(0); BAR();
            LOADA(0, 0, 1);              STAGE(Ar, s0 + 1); BAR(); MFMA8(1); BAR();
            LOADB(0, 1); LOADA(0, 1, 0); STAGE(Ar, s0 + 2); BAR(); MFMA8(0); BAR();
            LOADA(0, 1, 1);              STAGE(Ar, s0 + 3); BAR(); MFMA8(1);
            VMCNT6(); BAR();
            // ---- K-tile 2t+1 (dbuf 1) ----
            LOADB(1, 0); LOADA(1, 0, 0); STAGE(Ar, s0 + 4); BAR(); MFMA8(0); BAR();
            LOADA(1, 0, 1);              STAGE(Ar, s0 + 5); BAR(); MFMA8(1); BAR();
            LOADB(1, 1); LOADA(1, 1, 0); STAGE(Ar, s0 + 6); BAR(); MFMA8(0); BAR();
            LOADA(1, 1, 1);              STAGE(Ar, s0 + 7); BAR(); MFMA8(1);
            VMCNT6(); BAR();
        }
        // ---- tail: K-tiles 14 (dbuf 0) & 15 (dbuf 1); stage slots:
        // s63 (this tile) then n0..n6 (next tile).
        LOADB(0, 0); LOADA(0, 0, 0); STAGE(Ar, 63); BAR(); MFMA8(0); BAR();
        LOADA(0, 0, 1);              STAGE(An, 0);  BAR(); MFMA8(1); BAR();
        LOADB(0, 1); LOADA(0, 1, 0); STAGE(An, 1);  BAR(); MFMA8(0); BAR();
        LOADA(0, 1, 1);              STAGE(An, 2);  BAR(); MFMA8(1);
        VMCNT6(); BAR();
        LOADB(1, 0); LOADA(1, 0, 0); STAGE(An, 3);  BAR(); MFMA8(0); BAR();
        LOADA(1, 0, 1);              STAGE(An, 4);  BAR(); MFMA8(1); BAR();
        LOADB(1, 1); LOADA(1, 1, 0); STAGE(An, 5);  BAR(); MFMA8(0); BAR();
        LOADA(1, 1, 1);              STAGE(An, 6);  BAR(); MFMA8(1);
        VMCNT6(); BAR();

        // Epilogue tile r: NT stores. C/D: col = lane&31 (128B segments),
        // row = mi*32 + q*8 + rr + (lane>>5)*4.
        const int c_row0 = (btm0 + 2 * r) * 256 + wr * 128 + ((lane >> 5) & 1) * 4;
#pragma unroll
        for (int mi = 0; mi < 4; ++mi) {
#pragma unroll
            for (int n = 0; n < 2; ++n) {
                f32x16 a = acc[mi][n];
#pragma unroll
                for (int q = 0; q < 4; ++q) {
#pragma unroll
                    for (int rr = 0; rr < 4; ++rr) {
                        const int row = c_row0 + mi * 32 + q * 8 + rr;
                        __builtin_nontemporal_store(a[q * 4 + rr] + bvr[n],
                            &C[(size_t)row * NDIM + c_colb + n * 32]);
                    }
                }
#pragma unroll
                for (int z = 0; z < 16; ++z) acc[mi][n][z] = 0.f;
            }
        }
    }
}

extern "C" void kernel_launch(void* const* d_in, const int* in_sizes, int n_in,
                              void* d_out, int out_size, void* d_ws, size_t ws_size,
                              hipStream_t stream) {
    const float* x      = (const float*)d_in[0];
    const float* values = (const float*)d_in[1];
    const float* bias   = (const float*)d_in[2];
    float* out = (float*)d_out;

    // ws: xg bf16 [16384][1024] = 32 MB @ 0; values bf16 [4096][1024] @ 32 MB
    u16* xg = (u16*)d_ws;
    u16* vb = (u16*)((char*)d_ws + ((size_t)32 << 20));

    prep_kernel<<<6144, 256, 0, stream>>>(x, (uint2*)xg, values, (uint4*)vb);
    gemm_kernel<<<256, 512, 0, stream>>>(xg, vb, bias, out);
}